// Round 2
// baseline (455.420 us; speedup 1.0000x reference)
//
#include <hip/hip_runtime.h>

// ---------------------------------------------------------------------------
// ConceptNetEncoder on MI355X.
//   tokens M=1024 (B=4,L=256), vocab V=100000, E=256, topk=16 (hardcoded).
// Pipeline:
//   prep:        table f32->f16, emb gather->f16, a^T -> f16
//   gemm_topk:   f16 MFMA logits GEMM fused with per-(token, 1024-v-group) top-8
//                candidates, packed as (monotone16(val)<<10 | local_idx)
//   select:      per token: key-top-32 of 784 candidates -> exact f32 re-rank
//                -> exact top-16 indices
//   gemm_ta:     ta[16384,256] = table_f16[hidx] @ a  (MFMA)
//   attn_pool:   e=tanh(ta)@b, softmax16, out = w @ table[hidx]  (all f32)
// ---------------------------------------------------------------------------

#define V_ROWS   100000
#define E_DIM    256
#define M_TOK    1024
#define NGROUPS  98            // 98*1024 >= 100000
#define VGROUP   1024
#define NCAND    (NGROUPS*8)   // 784 candidates per token

typedef _Float16 f16x8 __attribute__((ext_vector_type(8)));
typedef float    f32x4 __attribute__((ext_vector_type(4)));

// ---------------- prep: f32 -> f16 conversions ----------------
__global__ __launch_bounds__(256) void prep_kernel(
    const float* __restrict__ table, const int* __restrict__ text,
    const float* __restrict__ amat,
    _Float16* __restrict__ tabh, _Float16* __restrict__ embh,
    _Float16* __restrict__ ahT)
{
  const int NTAB = V_ROWS * E_DIM / 8;   // 3,200,000 8-elem units
  const int NEMB = M_TOK * E_DIM / 8;    // 32,768
  const int NA   = E_DIM * E_DIM;        // 65,536 scalar units
  const int NU   = NTAB + NEMB + NA;
  for (int u = blockIdx.x * 256 + threadIdx.x; u < NU; u += gridDim.x * 256) {
    if (u < NTAB + NEMB) {
      size_t srcoff; _Float16* dst;
      if (u < NTAB) {
        srcoff = (size_t)u * 8; dst = tabh + (size_t)u * 8;
      } else {
        int e2 = u - NTAB; int tt = e2 >> 5, kc = e2 & 31;
        srcoff = (size_t)text[tt] * E_DIM + kc * 8;
        dst = embh + (size_t)e2 * 8;
      }
      float4 x0 = *(const float4*)(table + srcoff);
      float4 x1 = *(const float4*)(table + srcoff + 4);
      f16x8 hv;
      hv[0]=(_Float16)x0.x; hv[1]=(_Float16)x0.y; hv[2]=(_Float16)x0.z; hv[3]=(_Float16)x0.w;
      hv[4]=(_Float16)x1.x; hv[5]=(_Float16)x1.y; hv[6]=(_Float16)x1.z; hv[7]=(_Float16)x1.w;
      *(f16x8*)dst = hv;
    } else {
      int e3 = u - NTAB - NEMB;          // e3 = k*256 + n (coalesced read of a)
      int k = e3 >> 8, n = e3 & 255;
      ahT[n * E_DIM + k] = (_Float16)amat[e3];   // transposed write
    }
  }
}

// ---------------- fused logits GEMM + per-group top-8 ----------------
// block: 256 thr (4 waves). m-tile 64 tokens, 4 n-tiles of 256 v = group 1024.
// wave w owns tile cols [w*64, w*64+64). MFMA 16x16x32 f16.
__global__ __launch_bounds__(256, 2) void gemm_topk_kernel(
    const _Float16* __restrict__ tabh, const _Float16* __restrict__ embh,
    unsigned int* __restrict__ cand)
{
  const int mtile = blockIdx.x;          // 0..15
  const int group = blockIdx.y;          // 0..97
  const int tid = threadIdx.x;
  const int w = tid >> 6, l = tid & 63;

  __shared__ uint4        Alds[64 * 32];       // 32 KB (swizzled 16B chunks)
  __shared__ float        Llds[64 * 132];      // 33 KB (128-col half dump, pad 4)
  __shared__ unsigned int Clds[256 * 8];       // 8 KB merge scratch

  // Load A tile (64 emb rows, all K=256) with XOR chunk swizzle.
  {
    const uint4* srcA = (const uint4*)embh + (size_t)mtile * 64 * 32;
    #pragma unroll
    for (int i = 0; i < 8; ++i) {
      int c = i * 256 + tid;               // 0..2047 = r*32 + kc
      int r = c >> 5, kc = c & 31;
      Alds[r * 32 + (kc ^ (r & 7))] = srcA[c];
    }
  }
  __syncthreads();

  unsigned int t8[8] = {0, 0, 0, 0, 0, 0, 0, 0};  // per-thread top-8 packed keys
  const int sr = tid >> 2;   // scan row 0..63
  const int ss = tid & 3;    // scan slice (cols == ss mod 4)

  for (int g = 0; g < 4; ++g) {
    const int vb = group * VGROUP + g * 256 + w * 64;
    f32x4 acc[4][4] = {};

    #pragma unroll
    for (int kk = 0; kk < 8; ++kk) {
      f16x8 af[4], bf[4];
      int kc = kk * 4 + (l >> 4);
      #pragma unroll
      for (int fm = 0; fm < 4; ++fm) {
        int r = fm * 16 + (l & 15);
        af[fm] = *reinterpret_cast<const f16x8*>(&Alds[r * 32 + (kc ^ (r & 7))]);
      }
      #pragma unroll
      for (int fn = 0; fn < 4; ++fn) {
        int v = vb + fn * 16 + (l & 15);
        int vv = v < V_ROWS ? v : 0;       // clamp; masked at scan time
        bf[fn] = *reinterpret_cast<const f16x8*>(
            tabh + (size_t)vv * E_DIM + kk * 32 + (l >> 4) * 8);
      }
      #pragma unroll
      for (int fm = 0; fm < 4; ++fm)
        #pragma unroll
        for (int fn = 0; fn < 4; ++fn)
          acc[fm][fn] = __builtin_amdgcn_mfma_f32_16x16x32_f16(
              af[fm], bf[fn], acc[fm][fn], 0, 0, 0);
    }

    // dump + scan in two 128-col halves (keeps LDS small)
    for (int h = 0; h < 2; ++h) {
      __syncthreads();
      if ((w >> 1) == h) {                 // waves 2h, 2h+1 own this half
        int cb = (w & 1) * 64;
        #pragma unroll
        for (int fm = 0; fm < 4; ++fm) {
          int row = fm * 16 + (l >> 4) * 4;
          #pragma unroll
          for (int fn = 0; fn < 4; ++fn) {
            int col = cb + fn * 16 + (l & 15);
            #pragma unroll
            for (int r2 = 0; r2 < 4; ++r2)
              Llds[(row + r2) * 132 + col] = acc[fm][fn][r2];
          }
        }
      }
      __syncthreads();
      int lbase = g * 256 + h * 128;       // local idx base within group
      #pragma unroll 4
      for (int j = 0; j < 32; ++j) {
        int cc = ss + 4 * j;
        int lidx = lbase + cc;
        if (group * VGROUP + lidx >= V_ROWS) continue;
        float val = Llds[sr * 132 + cc];
        // monotone 16-bit key from f32 bits (order-preserving, no NaNs here)
        unsigned int u = __builtin_bit_cast(unsigned int, val);
        unsigned int mu = u ^ ((u >> 31) ? 0xFFFFFFFFu : 0x80000000u);
        unsigned int key = ((mu >> 16) << 10) | (unsigned int)lidx;
        if (key > t8[7]) {
          #pragma unroll
          for (int q = 0; q < 8; ++q) {
            unsigned int mx = t8[q] > key ? t8[q] : key;
            unsigned int mn = t8[q] > key ? key : t8[q];
            t8[q] = mx; key = mn;
          }
        }
      }
    }
  }

  // merge 4 slices per row -> exact per-(row, group) top-8
  __syncthreads();
  #pragma unroll
  for (int i = 0; i < 8; ++i) Clds[tid * 8 + i] = t8[i];
  __syncthreads();
  if (tid < 64) {
    unsigned int best[8] = {0, 0, 0, 0, 0, 0, 0, 0};
    for (int s2 = 0; s2 < 4; ++s2)
      for (int i = 0; i < 8; ++i) {
        unsigned int key = Clds[(tid * 4 + s2) * 8 + i];
        if (key > best[7]) {
          #pragma unroll
          for (int q = 0; q < 8; ++q) {
            unsigned int mx = best[q] > key ? best[q] : key;
            unsigned int mn = best[q] > key ? key : best[q];
            best[q] = mx; key = mn;
          }
        }
      }
    int token = mtile * 64 + tid;
    unsigned int* dst = cand + ((size_t)token * NGROUPS + group) * 8;
    #pragma unroll
    for (int i = 0; i < 8; ++i) dst[i] = best[i];
  }
}

// ---------------- per-token: top-32 select + exact f32 re-rank -> top-16 ----
__global__ __launch_bounds__(256) void select_kernel(
    const float* __restrict__ table, const int* __restrict__ text,
    const unsigned int* __restrict__ cand, int* __restrict__ hidx)
{
  const int t = blockIdx.x, tid = threadIdx.x;
  const int lane = tid & 63, w = tid >> 6;
  __shared__ unsigned int ck[NCAND];
  __shared__ int selv[32];
  __shared__ float ex[32];
  __shared__ unsigned long long wred[4];

  for (int i = tid; i < NCAND; i += 256) ck[i] = cand[(size_t)t * NCAND + i];
  __syncthreads();

  for (int it = 0; it < 32; ++it) {
    unsigned long long best = 0;
    for (int i = tid; i < NCAND; i += 256) {
      unsigned long long p = ((unsigned long long)ck[i] << 10) | (unsigned int)i;
      if (p > best) best = p;
    }
    #pragma unroll
    for (int d = 32; d >= 1; d >>= 1) {
      unsigned long long o = __shfl_xor(best, d);
      if (o > best) best = o;
    }
    if (lane == 0) wred[w] = best;
    __syncthreads();
    if (tid == 0) {
      unsigned long long b = wred[0];
      for (int q = 1; q < 4; ++q) if (wred[q] > b) b = wred[q];
      int slot = (int)(b & 1023ull);
      unsigned int key = ck[slot];
      selv[it] = (slot >> 3) * VGROUP + (int)(key & 1023u);
      ck[slot] = 0;
    }
    __syncthreads();
  }

  // exact f32 dot for the 32 candidates: 8 threads per candidate
  {
    int c = tid >> 3, s = tid & 7;
    int tok = text[t];
    const float* er = table + (size_t)tok * E_DIM;
    const float* tr = table + (size_t)selv[c] * E_DIM;
    float acc = 0.f;
    #pragma unroll 8
    for (int k2 = 0; k2 < 32; ++k2) acc += er[s * 32 + k2] * tr[s * 32 + k2];
    #pragma unroll
    for (int d = 1; d < 8; d <<= 1) acc += __shfl_xor(acc, d);
    if (s == 0) ex[c] = acc;
  }
  __syncthreads();

  // exact top-16 of ex[0..31] on wave 0
  if (w == 0) {
    float val = (lane < 32) ? ex[lane] : -1e38f;
    for (int it = 0; it < 16; ++it) {
      float m = val;
      #pragma unroll
      for (int d = 1; d < 32; d <<= 1) { float o = __shfl_xor(m, d); m = o > m ? o : m; }
      unsigned long long msk = __ballot(lane < 32 && val == m);
      int winner = __ffsll(msk) - 1;
      if (lane == 0) hidx[t * 16 + it] = selv[winner];
      if (lane == winner) val = -1e38f;
    }
  }
}

// ---------------- ta = gather(table_f16, hidx) @ a  (MFMA, f32 out) --------
__global__ __launch_bounds__(256, 2) void gemm_ta_kernel(
    const _Float16* __restrict__ tabh, const _Float16* __restrict__ ahT,
    const int* __restrict__ hidx, float* __restrict__ ta)
{
  const int mtile = blockIdx.x;          // 0..255, 64 gathered rows each
  const int tid = threadIdx.x;
  const int w = tid >> 6, l = tid & 63;
  __shared__ uint4 Alds[64 * 32];

  #pragma unroll
  for (int i = 0; i < 8; ++i) {
    int c = i * 256 + tid;
    int r = c >> 5, kc = c & 31;
    int src = hidx[mtile * 64 + r];
    Alds[r * 32 + (kc ^ (r & 7))] =
        *(const uint4*)(tabh + (size_t)src * E_DIM + kc * 8);
  }
  __syncthreads();

  f32x4 acc[4][4] = {};
  #pragma unroll
  for (int kk = 0; kk < 8; ++kk) {
    f16x8 af[4], bf[4];
    int kc = kk * 4 + (l >> 4);
    #pragma unroll
    for (int fm = 0; fm < 4; ++fm) {
      int r = fm * 16 + (l & 15);
      af[fm] = *reinterpret_cast<const f16x8*>(&Alds[r * 32 + (kc ^ (r & 7))]);
    }
    #pragma unroll
    for (int fn = 0; fn < 4; ++fn) {
      int n = w * 64 + fn * 16 + (l & 15);
      bf[fn] = *reinterpret_cast<const f16x8*>(
          ahT + (size_t)n * E_DIM + kk * 32 + (l >> 4) * 8);
    }
    #pragma unroll
    for (int fm = 0; fm < 4; ++fm)
      #pragma unroll
      for (int fn = 0; fn < 4; ++fn)
        acc[fm][fn] = __builtin_amdgcn_mfma_f32_16x16x32_f16(
            af[fm], bf[fn], acc[fm][fn], 0, 0, 0);
  }

  #pragma unroll
  for (int fm = 0; fm < 4; ++fm) {
    int row = mtile * 64 + fm * 16 + (l >> 4) * 4;
    #pragma unroll
    for (int fn = 0; fn < 4; ++fn) {
      int col = w * 64 + fn * 16 + (l & 15);
      #pragma unroll
      for (int r2 = 0; r2 < 4; ++r2)
        ta[(size_t)(row + r2) * E_DIM + col] = acc[fm][fn][r2];
    }
  }
}

// ---------------- attention pool (exact f32) ----------------
__global__ __launch_bounds__(256) void attn_pool_kernel(
    const float* __restrict__ table, const float* __restrict__ bvec,
    const int* __restrict__ hidx, const float* __restrict__ ta,
    float* __restrict__ out)
{
  const int t = blockIdx.x, tid = threadIdx.x;
  const int lane = tid & 63, w = tid >> 6;
  __shared__ float hl[16][257];
  __shared__ float part[16][4];
  __shared__ float wgt[16];

  #pragma unroll
  for (int i = 0; i < 16; ++i)
    hl[i][tid] = table[(size_t)hidx[t * 16 + i] * E_DIM + tid];

  float bj = bvec[tid];
  float s_[16];
  #pragma unroll
  for (int i = 0; i < 16; ++i) {
    float x = ta[((size_t)t * 16 + i) * E_DIM + tid];
    s_[i] = tanhf(x) * bj;
  }
  #pragma unroll
  for (int i = 0; i < 16; ++i) {
    float r = s_[i];
    #pragma unroll
    for (int d = 1; d < 64; d <<= 1) r += __shfl_xor(r, d);
    if (lane == 0) part[i][w] = r;
  }
  __syncthreads();
  if (tid < 16) {
    float e = part[tid][0] + part[tid][1] + part[tid][2] + part[tid][3];
    float m = e;
    #pragma unroll
    for (int d = 1; d < 16; d <<= 1) { float o = __shfl_xor(m, d); m = o > m ? o : m; }
    float p = expf(e - m);
    float sum = p;
    #pragma unroll
    for (int d = 1; d < 16; d <<= 1) sum += __shfl_xor(sum, d);
    wgt[tid] = p / sum;
  }
  __syncthreads();
  float o = 0.f;
  #pragma unroll
  for (int i = 0; i < 16; ++i) o += wgt[i] * hl[i][tid];
  out[(size_t)t * E_DIM + tid] = o;
}

// ---------------------------------------------------------------------------
extern "C" void kernel_launch(void* const* d_in, const int* in_sizes, int n_in,
                              void* d_out, int out_size, void* d_ws, size_t ws_size,
                              hipStream_t stream) {
  const int*   text  = (const int*)d_in[0];
  const float* table = (const float*)d_in[1];
  const float* amat  = (const float*)d_in[2];
  const float* bvec  = (const float*)d_in[3];
  float*       out   = (float*)d_out;

  char* ws = (char*)d_ws;
  // workspace layout (all 16B aligned), total ~72 MB
  _Float16*     tabh = (_Float16*)(ws + 0);                    // 51,200,000 B
  _Float16*     embh = (_Float16*)(ws + 51200000);             //    524,288 B
  _Float16*     ahT  = (_Float16*)(ws + 51724288);             //    131,072 B
  unsigned int* cand = (unsigned int*)(ws + 51855360);         //  3,211,264 B
  int*          hidx = (int*)(ws + 55066624);                  //     65,536 B
  float*        ta   = (float*)(ws + 55132160);                // 16,777,216 B

  prep_kernel<<<2048, 256, 0, stream>>>(table, text, amat, tabh, embh, ahT);
  gemm_topk_kernel<<<dim3(16, NGROUPS), 256, 0, stream>>>(tabh, embh, cand);
  select_kernel<<<M_TOK, 256, 0, stream>>>(table, text, cand, hidx);
  gemm_ta_kernel<<<256, 256, 0, stream>>>(tabh, ahT, hidx, ta);
  attn_pool_kernel<<<M_TOK, 256, 0, stream>>>(table, bvec, hidx, ta, out);
}

// Round 3
// 420.324 us; speedup vs baseline: 1.0835x; 1.0835x over previous
//
#include <hip/hip_runtime.h>

// ---------------------------------------------------------------------------
// ConceptNetEncoder on MI355X.
//   tokens M=1024 (B=4,L=256), vocab V=100000, E=256, topk=16 (hardcoded).
// Pipeline:
//   prep:        table f32->f16, emb gather->f16, a^T -> f16
//   gemm_topk:   f16 MFMA logits GEMM fused with per-(token, 1024-v-group) top-8
//                candidates, keys = (bits(val+2.5)>>7 & 0xFFFF)*1024 | local_idx
//                (monotone for val in (-0.5, 1.5) — logits are in [-0.4, 1.4]).
//                XCD-swizzled grid: 16 mtiles of a group share one XCD's L2.
//   select:      per token: key-top-32 of 784 candidates -> exact f32 re-rank
//                -> exact top-16 indices
//   gemm_ta:     ta[16384,256] = table_f16[hidx] @ a  (MFMA)
//   attn_pool:   e=tanh(ta)@b, softmax16, out = w @ table[hidx]  (all f32)
// ---------------------------------------------------------------------------

#define V_ROWS   100000
#define E_DIM    256
#define M_TOK    1024
#define NGROUPS  98            // 98*1024 >= 100000
#define VGROUP   1024
#define NCAND    (NGROUPS*8)   // 784 candidates per token
#define KBIAS    2.5f
#define SENTINEL -0.45f        // packs below every real logit (>= -0.4)

typedef _Float16 f16x8 __attribute__((ext_vector_type(8)));
typedef float    f32x4 __attribute__((ext_vector_type(4)));

// ---------------- prep: f32 -> f16 conversions ----------------
__global__ __launch_bounds__(256) void prep_kernel(
    const float* __restrict__ table, const int* __restrict__ text,
    const float* __restrict__ amat,
    _Float16* __restrict__ tabh, _Float16* __restrict__ embh,
    _Float16* __restrict__ ahT)
{
  const int NTAB = V_ROWS * E_DIM / 8;   // 3,200,000 8-elem units
  const int NEMB = M_TOK * E_DIM / 8;    // 32,768
  const int NA   = E_DIM * E_DIM;        // 65,536 scalar units
  const int NU   = NTAB + NEMB + NA;
  for (int u = blockIdx.x * 256 + threadIdx.x; u < NU; u += gridDim.x * 256) {
    if (u < NTAB + NEMB) {
      size_t srcoff; _Float16* dst;
      if (u < NTAB) {
        srcoff = (size_t)u * 8; dst = tabh + (size_t)u * 8;
      } else {
        int e2 = u - NTAB; int tt = e2 >> 5, kc = e2 & 31;
        srcoff = (size_t)text[tt] * E_DIM + kc * 8;
        dst = embh + (size_t)e2 * 8;
      }
      float4 x0 = *(const float4*)(table + srcoff);
      float4 x1 = *(const float4*)(table + srcoff + 4);
      f16x8 hv;
      hv[0]=(_Float16)x0.x; hv[1]=(_Float16)x0.y; hv[2]=(_Float16)x0.z; hv[3]=(_Float16)x0.w;
      hv[4]=(_Float16)x1.x; hv[5]=(_Float16)x1.y; hv[6]=(_Float16)x1.z; hv[7]=(_Float16)x1.w;
      *(f16x8*)dst = hv;
    } else {
      int e3 = u - NTAB - NEMB;          // e3 = k*256 + n (coalesced read of a)
      int k = e3 >> 8, n = e3 & 255;
      ahT[n * E_DIM + k] = (_Float16)amat[e3];   // transposed write
    }
  }
}

// Monotone 16-bit key for val in (-0.5, 1.5): bits(val+2.5) in [2.0,4.0) keep
// exponent 0x80, so bits[22:7] are order-preserving. Quantum 2^-15 ~ 3e-5.
__device__ __forceinline__ unsigned int pack_key(float val, int lidx) {
  float b = val + KBIAS;
  unsigned int u = __builtin_bit_cast(unsigned int, b);
  return (((u >> 7) & 0xFFFFu) << 10) | (unsigned int)lidx;
}
__device__ __forceinline__ float thr_from_key(unsigned int key) {
  unsigned int u = 0x40000000u | ((key >> 10) << 7);   // lower bound of bucket
  return __builtin_bit_cast(float, u) - KBIAS;
}

// ---------------- fused logits GEMM + per-group top-8 ----------------
// block: 256 thr (4 waves). m-tile 64 tokens; group = 1024 v cols as 4 g-iters
// of 256; wave w owns cols [w*64, w*64+64) each g-iter. MFMA 16x16x32 f16.
// B loads double-buffered across kk and prefetched across g; epilogue dumps
// each wave's 64x64 quarter to a chunk-XOR-swizzled f32 buffer, scanned with
// ds_read_b128 + max4 prefilter into per-thread top-8 (float threshold,
// pack-on-insert).
__global__ __launch_bounds__(256, 3) void gemm_topk_kernel(
    const _Float16* __restrict__ tabh, const _Float16* __restrict__ embh,
    unsigned int* __restrict__ cand)
{
  // XCD-aware decode: groups 0..95 pinned to XCD group/12 (bid&7); 96,97 tail.
  int bid = blockIdx.x;
  int group, mtile;
  if (bid < 1536) { int xcd = bid & 7, r = bid >> 3; mtile = r & 15; group = xcd * 12 + (r >> 4); }
  else            { int r = bid - 1536;              mtile = r & 15; group = 96 + (r >> 4); }

  const int tid = threadIdx.x;
  const int w = tid >> 6, l = tid & 63;

  __shared__ uint4 Alds[64 * 32];   // 32 KB, swizzled 16B chunks
  __shared__ float Lq[64 * 64];     // 16 KB quarter dump (chunk-XOR swizzle)

  // Load A tile (64 emb rows, all K=256) with XOR chunk swizzle.
  {
    const uint4* srcA = (const uint4*)embh + (size_t)mtile * 64 * 32;
    #pragma unroll
    for (int i = 0; i < 8; ++i) {
      int c = i * 256 + tid;               // 0..2047 = r*32 + kc
      int r = c >> 5, kc = c & 31;
      Alds[r * 32 + (kc ^ (r & 7))] = srcA[c];
    }
  }
  __syncthreads();

  unsigned int t8[8] = {0, 0, 0, 0, 0, 0, 0, 0};  // per-thread top-8 packed keys
  float thr = -0.5f;                                // == thr_from_key(0)
  const int sr = tid >> 2;   // scan row 0..63
  const int ss = tid & 3;    // scan col-slice within quarter

  auto ins = [&](unsigned int key) {
    unsigned int k = key;
    #pragma unroll
    for (int q2 = 0; q2 < 8; ++q2) {
      unsigned int mx = t8[q2] > k ? t8[q2] : k;
      unsigned int mn = t8[q2] > k ? k : t8[q2];
      t8[q2] = mx; k = mn;
    }
    thr = thr_from_key(t8[7]);
  };

  auto loadB = [&](int g, int kk, int fn) -> f16x8 {
    int v = group * VGROUP + g * 256 + w * 64 + fn * 16 + (l & 15);
    v = v < V_ROWS ? v : V_ROWS - 1;       // clamp; sentinel at dump time
    return *reinterpret_cast<const f16x8*>(
        tabh + (size_t)v * E_DIM + kk * 32 + (l >> 4) * 8);
  };

  f16x8 bf[4];
  #pragma unroll
  for (int fn = 0; fn < 4; ++fn) bf[fn] = loadB(0, 0, fn);

  for (int g = 0; g < 4; ++g) {
    f32x4 acc[4][4] = {};

    #pragma unroll
    for (int kk = 0; kk < 8; ++kk) {
      f16x8 bcur[4];
      #pragma unroll
      for (int fn = 0; fn < 4; ++fn) bcur[fn] = bf[fn];
      // prefetch next kk (or next g's kk=0) while current MFMAs run
      if (kk < 7) {
        #pragma unroll
        for (int fn = 0; fn < 4; ++fn) bf[fn] = loadB(g, kk + 1, fn);
      } else if (g < 3) {
        #pragma unroll
        for (int fn = 0; fn < 4; ++fn) bf[fn] = loadB(g + 1, 0, fn);
      }
      int kc = kk * 4 + (l >> 4);
      #pragma unroll
      for (int fm = 0; fm < 4; ++fm) {
        int r = fm * 16 + (l & 15);
        f16x8 af = *reinterpret_cast<const f16x8*>(&Alds[r * 32 + (kc ^ (r & 7))]);
        #pragma unroll
        for (int fn = 0; fn < 4; ++fn)
          acc[fm][fn] = __builtin_amdgcn_mfma_f32_16x16x32_f16(
              af, bcur[fn], acc[fm][fn], 0, 0, 0);
      }
    }

    // 4 quarters: wave q dumps its own 64x64 to Lq, then all scan it.
    for (int q = 0; q < 4; ++q) {
      __syncthreads();                     // Lq free (previous scan done)
      if (w == q) {
        #pragma unroll
        for (int fm = 0; fm < 4; ++fm)
          #pragma unroll
          for (int fn = 0; fn < 4; ++fn) {
            int cq = fn * 16 + (l & 15);
            int gcol = group * VGROUP + g * 256 + q * 64 + cq;
            #pragma unroll
            for (int r2 = 0; r2 < 4; ++r2) {
              int row = fm * 16 + (l >> 4) * 4 + r2;
              float val = (gcol < V_ROWS) ? acc[fm][fn][r2] : SENTINEL;
              Lq[row * 64 + (((cq >> 2) ^ (row & 7)) << 2) + (cq & 3)] = val;
            }
          }
      }
      __syncthreads();                     // Lq ready
      const float4* Lq4 = (const float4*)Lq;
      int lbase = g * 256 + q * 64 + ss * 16;
      #pragma unroll
      for (int j = 0; j < 4; ++j) {
        float4 v = Lq4[sr * 16 + ((ss * 4 + j) ^ (sr & 7))];
        float m = fmaxf(fmaxf(v.x, v.y), fmaxf(v.z, v.w));
        if (m > thr) {
          int cb = lbase + 4 * j;
          if (v.x > thr) ins(pack_key(v.x, cb));
          if (v.y > thr) ins(pack_key(v.y, cb + 1));
          if (v.z > thr) ins(pack_key(v.z, cb + 2));
          if (v.w > thr) ins(pack_key(v.w, cb + 3));
        }
      }
    }
  }

  // merge 4 slices per row -> exact per-(row, group) top-8 (Clds overlays Lq)
  __syncthreads();
  unsigned int* Clds = (unsigned int*)Lq;
  #pragma unroll
  for (int i = 0; i < 8; ++i) Clds[tid * 8 + i] = t8[i];
  __syncthreads();
  if (tid < 64) {
    unsigned int best[8] = {0, 0, 0, 0, 0, 0, 0, 0};
    for (int s2 = 0; s2 < 4; ++s2)
      for (int i = 0; i < 8; ++i) {
        unsigned int key = Clds[(tid * 4 + s2) * 8 + i];
        if (key > best[7]) {
          #pragma unroll
          for (int q2 = 0; q2 < 8; ++q2) {
            unsigned int mx = best[q2] > key ? best[q2] : key;
            unsigned int mn = best[q2] > key ? key : best[q2];
            best[q2] = mx; key = mn;
          }
        }
      }
    int token = mtile * 64 + tid;
    unsigned int* dst = cand + ((size_t)token * NGROUPS + group) * 8;
    #pragma unroll
    for (int i = 0; i < 8; ++i) dst[i] = best[i];
  }
}

// ---------------- per-token: top-32 select + exact f32 re-rank -> top-16 ----
__global__ __launch_bounds__(256) void select_kernel(
    const float* __restrict__ table, const int* __restrict__ text,
    const unsigned int* __restrict__ cand, int* __restrict__ hidx)
{
  const int t = blockIdx.x, tid = threadIdx.x;
  const int lane = tid & 63, w = tid >> 6;
  __shared__ unsigned int ck[NCAND];
  __shared__ int selv[32];
  __shared__ float ex[32];
  __shared__ unsigned long long wred[4];

  for (int i = tid; i < NCAND; i += 256) ck[i] = cand[(size_t)t * NCAND + i];
  __syncthreads();

  for (int it = 0; it < 32; ++it) {
    unsigned long long best = 0;
    for (int i = tid; i < NCAND; i += 256) {
      unsigned long long p = ((unsigned long long)ck[i] << 10) | (unsigned int)i;
      if (p > best) best = p;
    }
    #pragma unroll
    for (int d = 32; d >= 1; d >>= 1) {
      unsigned long long o = __shfl_xor(best, d);
      if (o > best) best = o;
    }
    if (lane == 0) wred[w] = best;
    __syncthreads();
    if (tid == 0) {
      unsigned long long b = wred[0];
      for (int q = 1; q < 4; ++q) if (wred[q] > b) b = wred[q];
      int slot = (int)(b & 1023ull);
      unsigned int key = ck[slot];
      selv[it] = (slot >> 3) * VGROUP + (int)(key & 1023u);
      ck[slot] = 0;
    }
    __syncthreads();
  }

  // exact f32 dot for the 32 candidates: 8 threads per candidate
  {
    int c = tid >> 3, s = tid & 7;
    int tok = text[t];
    const float* er = table + (size_t)tok * E_DIM;
    const float* tr = table + (size_t)selv[c] * E_DIM;
    float acc = 0.f;
    #pragma unroll 8
    for (int k2 = 0; k2 < 32; ++k2) acc += er[s * 32 + k2] * tr[s * 32 + k2];
    #pragma unroll
    for (int d = 1; d < 8; d <<= 1) acc += __shfl_xor(acc, d);
    if (s == 0) ex[c] = acc;
  }
  __syncthreads();

  // exact top-16 of ex[0..31] on wave 0
  if (w == 0) {
    float val = (lane < 32) ? ex[lane] : -1e38f;
    for (int it = 0; it < 16; ++it) {
      float m = val;
      #pragma unroll
      for (int d = 1; d < 32; d <<= 1) { float o = __shfl_xor(m, d); m = o > m ? o : m; }
      unsigned long long msk = __ballot(lane < 32 && val == m);
      int winner = __ffsll(msk) - 1;
      if (lane == 0) hidx[t * 16 + it] = selv[winner];
      if (lane == winner) val = -1e38f;
    }
  }
}

// ---------------- ta = gather(table_f16, hidx) @ a  (MFMA, f32 out) --------
__global__ __launch_bounds__(256, 2) void gemm_ta_kernel(
    const _Float16* __restrict__ tabh, const _Float16* __restrict__ ahT,
    const int* __restrict__ hidx, float* __restrict__ ta)
{
  const int mtile = blockIdx.x;          // 0..255, 64 gathered rows each
  const int tid = threadIdx.x;
  const int w = tid >> 6, l = tid & 63;
  __shared__ uint4 Alds[64 * 32];

  #pragma unroll
  for (int i = 0; i < 8; ++i) {
    int c = i * 256 + tid;
    int r = c >> 5, kc = c & 31;
    int src = hidx[mtile * 64 + r];
    Alds[r * 32 + (kc ^ (r & 7))] =
        *(const uint4*)(tabh + (size_t)src * E_DIM + kc * 8);
  }
  __syncthreads();

  f32x4 acc[4][4] = {};
  #pragma unroll
  for (int kk = 0; kk < 8; ++kk) {
    f16x8 af[4], bf[4];
    int kc = kk * 4 + (l >> 4);
    #pragma unroll
    for (int fm = 0; fm < 4; ++fm) {
      int r = fm * 16 + (l & 15);
      af[fm] = *reinterpret_cast<const f16x8*>(&Alds[r * 32 + (kc ^ (r & 7))]);
    }
    #pragma unroll
    for (int fn = 0; fn < 4; ++fn) {
      int n = w * 64 + fn * 16 + (l & 15);
      bf[fn] = *reinterpret_cast<const f16x8*>(
          ahT + (size_t)n * E_DIM + kk * 32 + (l >> 4) * 8);
    }
    #pragma unroll
    for (int fm = 0; fm < 4; ++fm)
      #pragma unroll
      for (int fn = 0; fn < 4; ++fn)
        acc[fm][fn] = __builtin_amdgcn_mfma_f32_16x16x32_f16(
            af[fm], bf[fn], acc[fm][fn], 0, 0, 0);
  }

  #pragma unroll
  for (int fm = 0; fm < 4; ++fm) {
    int row = mtile * 64 + fm * 16 + (l >> 4) * 4;
    #pragma unroll
    for (int fn = 0; fn < 4; ++fn) {
      int col = w * 64 + fn * 16 + (l & 15);
      #pragma unroll
      for (int r2 = 0; r2 < 4; ++r2)
        ta[(size_t)(row + r2) * E_DIM + col] = acc[fm][fn][r2];
    }
  }
}

// ---------------- attention pool (exact f32) ----------------
__global__ __launch_bounds__(256) void attn_pool_kernel(
    const float* __restrict__ table, const float* __restrict__ bvec,
    const int* __restrict__ hidx, const float* __restrict__ ta,
    float* __restrict__ out)
{
  const int t = blockIdx.x, tid = threadIdx.x;
  const int lane = tid & 63, w = tid >> 6;
  __shared__ float hl[16][257];
  __shared__ float part[16][4];
  __shared__ float wgt[16];

  #pragma unroll
  for (int i = 0; i < 16; ++i)
    hl[i][tid] = table[(size_t)hidx[t * 16 + i] * E_DIM + tid];

  float bj = bvec[tid];
  float s_[16];
  #pragma unroll
  for (int i = 0; i < 16; ++i) {
    float x = ta[((size_t)t * 16 + i) * E_DIM + tid];
    s_[i] = tanhf(x) * bj;
  }
  #pragma unroll
  for (int i = 0; i < 16; ++i) {
    float r = s_[i];
    #pragma unroll
    for (int d = 1; d < 64; d <<= 1) r += __shfl_xor(r, d);
    if (lane == 0) part[i][w] = r;
  }
  __syncthreads();
  if (tid < 16) {
    float e = part[tid][0] + part[tid][1] + part[tid][2] + part[tid][3];
    float m = e;
    #pragma unroll
    for (int d = 1; d < 16; d <<= 1) { float o = __shfl_xor(m, d); m = o > m ? o : m; }
    float p = expf(e - m);
    float sum = p;
    #pragma unroll
    for (int d = 1; d < 16; d <<= 1) sum += __shfl_xor(sum, d);
    wgt[tid] = p / sum;
  }
  __syncthreads();
  float o = 0.f;
  #pragma unroll
  for (int i = 0; i < 16; ++i) o += wgt[i] * hl[i][tid];
  out[(size_t)t * E_DIM + tid] = o;
}

// ---------------------------------------------------------------------------
extern "C" void kernel_launch(void* const* d_in, const int* in_sizes, int n_in,
                              void* d_out, int out_size, void* d_ws, size_t ws_size,
                              hipStream_t stream) {
  const int*   text  = (const int*)d_in[0];
  const float* table = (const float*)d_in[1];
  const float* amat  = (const float*)d_in[2];
  const float* bvec  = (const float*)d_in[3];
  float*       out   = (float*)d_out;

  char* ws = (char*)d_ws;
  // workspace layout (all 16B aligned), total ~72 MB
  _Float16*     tabh = (_Float16*)(ws + 0);                    // 51,200,000 B
  _Float16*     embh = (_Float16*)(ws + 51200000);             //    524,288 B
  _Float16*     ahT  = (_Float16*)(ws + 51724288);             //    131,072 B
  unsigned int* cand = (unsigned int*)(ws + 51855360);         //  3,211,264 B
  int*          hidx = (int*)(ws + 55066624);                  //     65,536 B
  float*        ta   = (float*)(ws + 55132160);                // 16,777,216 B

  prep_kernel<<<2048, 256, 0, stream>>>(table, text, amat, tabh, embh, ahT);
  gemm_topk_kernel<<<16 * NGROUPS, 256, 0, stream>>>(tabh, embh, cand);
  select_kernel<<<M_TOK, 256, 0, stream>>>(table, text, cand, hidx);
  gemm_ta_kernel<<<256, 256, 0, stream>>>(tabh, ahT, hidx, ta);
  attn_pool_kernel<<<M_TOK, 256, 0, stream>>>(table, bvec, hidx, ta, out);
}